// Round 1
// baseline (90.216 us; speedup 1.0000x reference)
//
#include <hip/hip_runtime.h>

namespace {

constexpr int kT   = 8;    // timesteps
constexpr int kB   = 256;  // batch
constexpr int kNQ  = 8;    // qubits per circuit
constexpr int kNB  = 8;    // blocks
constexpr int kD   = 64;   // features = kNQ*kNB
constexpr int kNL  = 2;    // quantum layers
constexpr int kDepth = 2;  // StronglyEntanglingLayers depth
constexpr int kCirc = kT * kNB;            // 64 circuits per layer
constexpr int kGates = kDepth * kNQ;       // 16 Rot gates per circuit
constexpr int kGateF = 8;                  // floats per 2x2 complex gate

// ---------------- Rot-gate precompute ----------------
// qml.Rot(phi,theta,omega): U = [[ep*c, -conj(em)*s],[em*s, conj(ep)*c]]
// ep = exp(-0.5i(phi+omega)), em = exp(-0.5i(phi-omega))
__global__ void precompute_gates(const float* __restrict__ theta, float* __restrict__ gt) {
    int i = blockIdx.x * blockDim.x + threadIdx.x;
    if (i >= kNL * kCirc * kGates) return;
    int g = i & 15;          // d*8 + w
    int c = (i >> 4) & 63;   // circuit
    int l = i >> 10;         // layer
    int t = c >> 3, u = c & 7;
    int d = g >> 3, w = g & 7;
    // theta shape (T, NL, NB, DEPTH, NQ, 3)
    const float* th = theta + ((((t * kNL + l) * kNB + u) * kDepth + d) * kNQ + w) * 3;
    float phi = th[0], tht = th[1], omg = th[2];
    float st, ct, sp, cp, sm, cm;
    __sincosf(0.5f * tht, &st, &ct);
    __sincosf(0.5f * (phi + omg), &sp, &cp);
    __sincosf(0.5f * (phi - omg), &sm, &cm);
    float* o = gt + i * kGateF;
    o[0] =  ct * cp;  o[1] = -ct * sp;   // u00
    o[2] = -st * cm;  o[3] = -st * sm;   // u01
    o[4] =  st * cm;  o[5] = -st * sm;   // u10
    o[6] =  ct * cp;  o[7] =  ct * sp;   // u11
}

// ---------------- gate helpers ----------------
// state layout: amplitude k = (lane<<2) | reg, k bit p -> wire w = 7-p.
// p>=2 -> lane bit q=p-2 (cross-lane via shfl_xor); p<2 -> register bit.

// general complex 2x2 gate on a lane-bit wire (q = 5-w)
__device__ __forceinline__ void cgate_lane(float (&re)[4], float (&im)[4], int q, int lane,
                                           float u00r, float u00i, float u01r, float u01i,
                                           float u10r, float u10i, float u11r, float u11i) {
    const int mask = 1 << q;
    const int bit = (lane >> q) & 1;
    const float car = bit ? u11r : u00r;   // coeff * my amplitude
    const float cai = bit ? u11i : u00i;
    const float cbr = bit ? u10r : u01r;   // coeff * partner amplitude
    const float cbi = bit ? u10i : u01i;
#pragma unroll
    for (int r = 0; r < 4; ++r) {
        const float pre = __shfl_xor(re[r], mask, 64);
        const float pim = __shfl_xor(im[r], mask, 64);
        const float mre = re[r], mim = im[r];
        re[r] = car * mre - cai * mim + cbr * pre - cbi * pim;
        im[r] = car * mim + cai * mre + cbr * pim + cbi * pre;
    }
}

// general complex 2x2 gate on a register-bit wire (PB = 7-w, PB in {0,1})
template <int PB>
__device__ __forceinline__ void cgate_reg(float (&re)[4], float (&im)[4],
                                          float u00r, float u00i, float u01r, float u01i,
                                          float u10r, float u10i, float u11r, float u11i) {
#pragma unroll
    for (int lo = 0; lo < 4; ++lo) {
        if (lo & (1 << PB)) continue;
        const int hi = lo | (1 << PB);
        const float lre = re[lo], lim = im[lo];
        const float hre = re[hi], him = im[hi];
        re[lo] = u00r * lre - u00i * lim + u01r * hre - u01i * him;
        im[lo] = u00r * lim + u00i * lre + u01r * him + u01i * hre;
        re[hi] = u10r * lre - u10i * lim + u11r * hre - u11i * him;
        im[hi] = u10r * lim + u10i * lre + u11r * him + u11i * hre;
    }
}

// CNOT control wire CW, target wire TW (compile-time)
template <int CW, int TW>
__device__ __forceinline__ void cnot(float (&re)[4], float (&im)[4], int lane) {
    constexpr int pc = 7 - CW;
    constexpr int pt = 7 - TW;
    if constexpr (pt >= 2) {            // target on a lane bit
        constexpr int mask = 1 << (pt - 2);
        if constexpr (pc >= 2) {        // control on a lane bit
            const int ctrl = (lane >> (pc - 2)) & 1;
#pragma unroll
            for (int r = 0; r < 4; ++r) {
                const float pre = __shfl_xor(re[r], mask, 64);
                const float pim = __shfl_xor(im[r], mask, 64);
                re[r] = ctrl ? pre : re[r];
                im[r] = ctrl ? pim : im[r];
            }
        } else {                        // control on a register bit
#pragma unroll
            for (int r = 0; r < 4; ++r) {
                if (r & (1 << pc)) {
                    re[r] = __shfl_xor(re[r], mask, 64);
                    im[r] = __shfl_xor(im[r], mask, 64);
                }
            }
        }
    } else {                            // target on a register bit
        if constexpr (pc >= 2) {        // control on a lane bit: conditional reg swap
            const int ctrl = (lane >> (pc - 2)) & 1;
#pragma unroll
            for (int lo = 0; lo < 4; ++lo) {
                if (lo & (1 << pt)) continue;
                const int hi = lo | (1 << pt);
                const float ar = re[lo], br = re[hi];
                re[lo] = ctrl ? br : ar;  re[hi] = ctrl ? ar : br;
                const float ai = im[lo], bi = im[hi];
                im[lo] = ctrl ? bi : ai;  im[hi] = ctrl ? ai : bi;
            }
        } else {                        // both on register bits: static swap
#pragma unroll
            for (int lo = 0; lo < 4; ++lo) {
                if ((lo & (1 << pc)) && !(lo & (1 << pt))) {
                    const int hi = lo | (1 << pt);
                    float tr = re[lo]; re[lo] = re[hi]; re[hi] = tr;
                    float ti = im[lo]; im[lo] = im[hi]; im[hi] = ti;
                }
            }
        }
    }
}

__device__ __forceinline__ void cnot_ring1(float (&re)[4], float (&im)[4], int lane) {
    cnot<0, 1>(re, im, lane); cnot<1, 2>(re, im, lane);
    cnot<2, 3>(re, im, lane); cnot<3, 4>(re, im, lane);
    cnot<4, 5>(re, im, lane); cnot<5, 6>(re, im, lane);
    cnot<6, 7>(re, im, lane); cnot<7, 0>(re, im, lane);
}
__device__ __forceinline__ void cnot_ring2(float (&re)[4], float (&im)[4], int lane) {
    cnot<0, 2>(re, im, lane); cnot<1, 3>(re, im, lane);
    cnot<2, 4>(re, im, lane); cnot<3, 5>(re, im, lane);
    cnot<4, 6>(re, im, lane); cnot<5, 7>(re, im, lane);
    cnot<6, 0>(re, im, lane); cnot<7, 1>(re, im, lane);
}

// ---------------- main simulation kernel ----------------
// one wave = one (circuit, sample) statevector simulation
template <int LAYER>
__global__ __launch_bounds__(256) void sim_kernel(const float* __restrict__ act,
                                                  const float* __restrict__ gt,
                                                  float* __restrict__ out) {
    const int wave = (blockIdx.x << 2) | (threadIdx.x >> 6);
    const int lane = threadIdx.x & 63;
    const int b = wave & (kB - 1);     // sample
    const int c = wave >> 8;           // circuit 0..63
    const int t = c >> 3;              // timestep
    const int u = c & 7;               // block (L0) / feature (L1)

    // --- AngleEmbedding RY on |0..0> folded into a real product state ---
    // amp[k] = prod_w (bit_{7-w}(k) ? sin(a_w/2) : cos(a_w/2))
    float cw[8], sw[8];
    const float* ab = (LAYER == 0) ? act + (b * kT + t) * kD + u * kNQ
                                   : act + (t * kB + b) * kD + u;
    const int astride = (LAYER == 0) ? 1 : kNQ;
#pragma unroll
    for (int w = 0; w < 8; ++w) {
        __sincosf(0.5f * ab[w * astride], &sw[w], &cw[w]);
    }
    float lp = 1.0f;                   // product over lane-bit wires (w = 5-q)
#pragma unroll
    for (int q = 0; q < 6; ++q) {
        lp *= ((lane >> q) & 1) ? sw[5 - q] : cw[5 - q];
    }
    float re[4], im[4];
    re[0] = lp * cw[6] * cw[7];
    re[1] = lp * cw[6] * sw[7];
    re[2] = lp * sw[6] * cw[7];
    re[3] = lp * sw[6] * sw[7];
    im[0] = im[1] = im[2] = im[3] = 0.0f;

    // --- StronglyEntanglingLayers ---
    const float* g = gt + ((LAYER * kCirc + c) * kGates) * kGateF;
#pragma unroll
    for (int d = 0; d < kDepth; ++d) {
#pragma unroll
        for (int w = 0; w < 8; ++w) {
            const float4 g0 = *reinterpret_cast<const float4*>(g + (d * 8 + w) * kGateF);
            const float4 g1 = *reinterpret_cast<const float4*>(g + (d * 8 + w) * kGateF + 4);
            if (w < 6) {
                cgate_lane(re, im, 5 - w, lane, g0.x, g0.y, g0.z, g0.w, g1.x, g1.y, g1.z, g1.w);
            } else if (w == 6) {
                cgate_reg<1>(re, im, g0.x, g0.y, g0.z, g0.w, g1.x, g1.y, g1.z, g1.w);
            } else {
                cgate_reg<0>(re, im, g0.x, g0.y, g0.z, g0.w, g1.x, g1.y, g1.z, g1.w);
            }
        }
        if (d == 0) cnot_ring1(re, im, lane);
        else        cnot_ring2(re, im, lane);
    }

    // --- PauliZ expvals: ev[w] = sum_k |amp_k|^2 * (-1)^{bit_{7-w}(k)} ---
    const float p0 = re[0] * re[0] + im[0] * im[0];
    const float p1 = re[1] * re[1] + im[1] * im[1];
    const float p2 = re[2] * re[2] + im[2] * im[2];
    const float p3 = re[3] * re[3] + im[3] * im[3];
    const float ptot = p0 + p1 + p2 + p3;
    float e6 = p0 + p1 - p2 - p3;   // wire 6 (reg bit 1)
    float e7 = p0 - p1 + p2 - p3;   // wire 7 (reg bit 0)
#pragma unroll
    for (int m = 1; m < 64; m <<= 1) {
        e6 += __shfl_xor(e6, m, 64);
        e7 += __shfl_xor(e7, m, 64);
    }

    float* ob = (LAYER == 0) ? out + (t * kB + b) * kD + u * kNQ   // H0 (T,B,D)
                             : out + (b * kT + t) * kD + u * kNQ;  // final (B,T,D)
#pragma unroll
    for (int w = 0; w < 6; ++w) {
        const int q = 5 - w;
        float v = ((lane >> q) & 1) ? -ptot : ptot;
#pragma unroll
        for (int m = 1; m < 64; m <<= 1) v += __shfl_xor(v, m, 64);
        if (lane == 0) ob[w] = v;
    }
    if (lane == 0) { ob[6] = e6; ob[7] = e7; }
}

}  // namespace

extern "C" void kernel_launch(void* const* d_in, const int* in_sizes, int n_in,
                              void* d_out, int out_size, void* d_ws, size_t ws_size,
                              hipStream_t stream) {
    const float* x     = (const float*)d_in[0];   // (B, T, D) fp32
    const float* theta = (const float*)d_in[1];   // (T, NL, NB, DEPTH, NQ, 3) fp32
    float* out = (float*)d_out;                   // (B, T, D) fp32

    float* gt = (float*)d_ws;                     // gate table: 2*64*16*8 = 16384 floats (64 KB)
    float* h0 = gt + kNL * kCirc * kGates * kGateF;  // intermediate H0: (T,B,D) = 131072 floats

    // 2048 gate matrices
    precompute_gates<<<(kNL * kCirc * kGates + 255) / 256, 256, 0, stream>>>(theta, gt);
    // layer 0: 64 circuits x 256 samples = 16384 waves = 4096 blocks of 256
    sim_kernel<0><<<(kCirc * kB) / 4, 256, 0, stream>>>(x, gt, h0);
    // layer 1
    sim_kernel<1><<<(kCirc * kB) / 4, 256, 0, stream>>>(h0, gt, out);
}

// Round 2
// 74.220 us; speedup vs baseline: 1.2155x; 1.2155x over previous
//
#include <hip/hip_runtime.h>

namespace {

constexpr int kT   = 8;    // timesteps
constexpr int kB   = 256;  // batch
constexpr int kNQ  = 8;    // qubits per circuit
constexpr int kNB  = 8;    // blocks
constexpr int kD   = 64;   // features
constexpr int kNL  = 2;    // quantum layers
constexpr int kDepth = 2;
constexpr int kCirc = kT * kNB;        // 64 circuits per layer
constexpr int kGates = kDepth * kNQ;   // 16 Rot gates per circuit
constexpr int kGateF = 8;

// ---------------- Rot-gate precompute ----------------
__global__ void precompute_gates(const float* __restrict__ theta, float* __restrict__ gt) {
    int i = blockIdx.x * blockDim.x + threadIdx.x;
    if (i >= kNL * kCirc * kGates) return;
    int g = i & 15;
    int c = (i >> 4) & 63;
    int l = i >> 10;
    int t = c >> 3, u = c & 7;
    int d = g >> 3, w = g & 7;
    const float* th = theta + ((((t * kNL + l) * kNB + u) * kDepth + d) * kNQ + w) * 3;
    float phi = th[0], tht = th[1], omg = th[2];
    float st, ct, sp, cp, sm, cm;
    __sincosf(0.5f * tht, &st, &ct);
    __sincosf(0.5f * (phi + omg), &sp, &cp);
    __sincosf(0.5f * (phi - omg), &sm, &cm);
    float* o = gt + i * kGateF;
    o[0] =  ct * cp;  o[1] = -ct * sp;
    o[2] = -st * cm;  o[3] = -st * sm;
    o[4] =  st * cm;  o[5] = -st * sm;
    o[6] =  ct * cp;  o[7] =  ct * sp;
}

// ---------------- gate helpers (2 samples per wave) ----------------
// amp index k = (lane<<2)|reg; k bit p -> wire 7-p. Wires 0..5 = lane bits 5..0,
// wires 6,7 = reg bits 1,0.

__device__ __forceinline__ void cgate_lane2(float (&re)[2][4], float (&im)[2][4],
                                            int q, int lane,
                                            float u00r, float u00i, float u01r, float u01i,
                                            float u10r, float u10i, float u11r, float u11i) {
    const int mask = 1 << q;
    const int bit = (lane >> q) & 1;
    const float car = bit ? u11r : u00r;
    const float cai = bit ? u11i : u00i;
    const float cbr = bit ? u10r : u01r;
    const float cbi = bit ? u10i : u01i;
#pragma unroll
    for (int s = 0; s < 2; ++s)
#pragma unroll
        for (int r = 0; r < 4; ++r) {
            const float pre = __shfl_xor(re[s][r], mask, 64);
            const float pim = __shfl_xor(im[s][r], mask, 64);
            const float mre = re[s][r], mim = im[s][r];
            re[s][r] = car * mre - cai * mim + cbr * pre - cbi * pim;
            im[s][r] = car * mim + cai * mre + cbr * pim + cbi * pre;
        }
}

template <int PB>
__device__ __forceinline__ void cgate_reg2(float (&re)[2][4], float (&im)[2][4],
                                           float u00r, float u00i, float u01r, float u01i,
                                           float u10r, float u10i, float u11r, float u11i) {
#pragma unroll
    for (int s = 0; s < 2; ++s)
#pragma unroll
        for (int lo = 0; lo < 4; ++lo) {
            if (lo & (1 << PB)) continue;
            const int hi = lo | (1 << PB);
            const float lre = re[s][lo], lim = im[s][lo];
            const float hre = re[s][hi], him = im[s][hi];
            re[s][lo] = u00r * lre - u00i * lim + u01r * hre - u01i * him;
            im[s][lo] = u00r * lim + u00i * lre + u01r * him + u01i * hre;
            re[s][hi] = u10r * lre - u10i * lim + u11r * hre - u11i * him;
            im[s][hi] = u10r * lim + u10i * lre + u11r * him + u11i * hre;
        }
}

// apply lane-only permutation: new[lane] = old[addr]
__device__ __forceinline__ void perm_lanes2(float (&re)[2][4], float (&im)[2][4], int addr) {
#pragma unroll
    for (int s = 0; s < 2; ++s)
#pragma unroll
        for (int r = 0; r < 4; ++r) {
            re[s][r] = __shfl(re[s][r], addr, 64);
            im[s][r] = __shfl(im[s][r], addr, 64);
        }
}

// CNOT with lane-bit control (ctrl), register-bit target PB: conditional reg swap
template <int PB>
__device__ __forceinline__ void creg_target2(float (&re)[2][4], float (&im)[2][4], int ctrl) {
#pragma unroll
    for (int s = 0; s < 2; ++s)
#pragma unroll
        for (int lo = 0; lo < 4; ++lo) {
            if (lo & (1 << PB)) continue;
            const int hi = lo | (1 << PB);
            const float ar = re[s][lo], br = re[s][hi];
            re[s][lo] = ctrl ? br : ar;  re[s][hi] = ctrl ? ar : br;
            const float ai = im[s][lo], bi = im[s][hi];
            im[s][lo] = ctrl ? bi : ai;  im[s][hi] = ctrl ? ai : bi;
        }
}

// ---------------- main simulation kernel ----------------
// 4 waves/block, 2 samples/wave, circuit uniform per block (c = blockIdx >> 5)
template <int LAYER>
__global__ __launch_bounds__(256) void sim_kernel(const float* __restrict__ act,
                                                  const float* __restrict__ gt,
                                                  float* __restrict__ out) {
    const int widx = __builtin_amdgcn_readfirstlane(threadIdx.x >> 6);  // wave in block (SGPR)
    const int lane = threadIdx.x & 63;
    const int c = blockIdx.x >> 5;                         // circuit (block-uniform)
    const int b0 = ((blockIdx.x & 31) << 3) | (widx << 1); // first sample of this wave
    const int t = c >> 3;
    const int u = c & 7;

    // --- AngleEmbedding RY folded into real product state (2 samples) ---
    float re[2][4], im[2][4];
#pragma unroll
    for (int s = 0; s < 2; ++s) {
        const int b = b0 + s;
        const float* ab = (LAYER == 0) ? act + (b * kT + t) * kD + u * kNQ
                                       : act + (t * kB + b) * kD + u;
        const int astride = (LAYER == 0) ? 1 : kNQ;
        float cw[8], sw[8];
#pragma unroll
        for (int w = 0; w < 8; ++w) {
            __sincosf(0.5f * ab[w * astride], &sw[w], &cw[w]);
        }
        float lp = 1.0f;
#pragma unroll
        for (int q = 0; q < 6; ++q) {
            lp *= ((lane >> q) & 1) ? sw[5 - q] : cw[5 - q];
        }
        re[s][0] = lp * cw[6] * cw[7];
        re[s][1] = lp * cw[6] * sw[7];
        re[s][2] = lp * sw[6] * cw[7];
        re[s][3] = lp * sw[6] * sw[7];
        im[s][0] = im[s][1] = im[s][2] = im[s][3] = 0.0f;
    }

    // precomputed CNOT-chain permutation addresses (shared by both samples)
    // ring1 lane part: CNOT(0,1),(1,2),(2,3),(3,4),(4,5)  [wire w -> lane bit 5-w]
    int a1 = lane;
    a1 ^= (a1 >> 1) & 1;          // (4,5)
    a1 ^= ((a1 >> 2) & 1) << 1;   // (3,4)
    a1 ^= ((a1 >> 3) & 1) << 2;   // (2,3)
    a1 ^= ((a1 >> 4) & 1) << 3;   // (1,2)
    a1 ^= ((a1 >> 5) & 1) << 4;   // (0,1)
    // ring2 lane part: CNOT(0,2),(1,3),(2,4),(3,5)
    int a2 = lane;
    a2 ^= (a2 >> 2) & 1;          // (3,5)
    a2 ^= ((a2 >> 3) & 1) << 1;   // (2,4)
    a2 ^= ((a2 >> 4) & 1) << 2;   // (1,3)
    a2 ^= ((a2 >> 5) & 1) << 3;   // (0,2)

    // --- StronglyEntanglingLayers (gate table is block-uniform -> s_loads) ---
    const float* gbase = gt + (size_t)(LAYER * kCirc + c) * kGates * kGateF;
#pragma unroll
    for (int d = 0; d < kDepth; ++d) {
#pragma unroll
        for (int w = 0; w < 8; ++w) {
            const float* gp = gbase + (d * 8 + w) * kGateF;
            const float u00r = gp[0], u00i = gp[1], u01r = gp[2], u01i = gp[3];
            const float u10r = gp[4], u10i = gp[5], u11r = gp[6], u11i = gp[7];
            if (w < 6) {
                cgate_lane2(re, im, 5 - w, lane, u00r, u00i, u01r, u01i, u10r, u10i, u11r, u11i);
            } else if (w == 6) {
                cgate_reg2<1>(re, im, u00r, u00i, u01r, u01i, u10r, u10i, u11r, u11i);
            } else {
                cgate_reg2<0>(re, im, u00r, u00i, u01r, u01i, u10r, u10i, u11r, u11i);
            }
        }
        if (d == 0) {
            // ring1: composed lane CNOTs, then (5,6),(6,7),(7,0)
            perm_lanes2(re, im, a1);
            creg_target2<1>(re, im, lane & 1);          // (5,6): ctrl wire5 = lane bit 0
#pragma unroll
            for (int s = 0; s < 2; ++s) {               // (6,7): static swap regs 2<->3
                float tr = re[s][2]; re[s][2] = re[s][3]; re[s][3] = tr;
                float ti = im[s][2]; im[s][2] = im[s][3]; im[s][3] = ti;
            }
#pragma unroll
            for (int s = 0; s < 2; ++s) {               // (7,0): regs 1,3 swap across lane^32
                re[s][1] = __shfl_xor(re[s][1], 32, 64);
                im[s][1] = __shfl_xor(im[s][1], 32, 64);
                re[s][3] = __shfl_xor(re[s][3], 32, 64);
                im[s][3] = __shfl_xor(im[s][3], 32, 64);
            }
        } else {
            // ring2: composed lane CNOTs, then (4,6),(5,7),(6,0)+(7,1)
            perm_lanes2(re, im, a2);
            creg_target2<1>(re, im, (lane >> 1) & 1);   // (4,6): ctrl wire4 = lane bit 1
            creg_target2<0>(re, im, lane & 1);          // (5,7): ctrl wire5 = lane bit 0
#pragma unroll
            for (int s = 0; s < 2; ++s) {               // (6,0): regs 2,3 ^32; (7,1): regs 1,3 ^16
                re[s][1] = __shfl_xor(re[s][1], 16, 64);
                im[s][1] = __shfl_xor(im[s][1], 16, 64);
                re[s][2] = __shfl_xor(re[s][2], 32, 64);
                im[s][2] = __shfl_xor(im[s][2], 32, 64);
                re[s][3] = __shfl_xor(re[s][3], 48, 64);
                im[s][3] = __shfl_xor(im[s][3], 48, 64);
            }
        }
    }

    // --- PauliZ expvals via fused diff-tracking reduction tree ---
#pragma unroll
    for (int s = 0; s < 2; ++s) {
        const float p0 = re[s][0] * re[s][0] + im[s][0] * im[s][0];
        const float p1 = re[s][1] * re[s][1] + im[s][1] * im[s][1];
        const float p2 = re[s][2] * re[s][2] + im[s][2] * im[s][2];
        const float p3 = re[s][3] * re[s][3] + im[s][3] * im[s][3];
        const float a01 = p0 + p1, a23 = p2 + p3;
        float sum = a01 + a23;
        float e6 = a01 - a23;                 // wire 6 (reg bit 1)
        float e7 = (p0 - p1) + (p2 - p3);     // wire 7 (reg bit 0)
        float E[6];
#pragma unroll
        for (int q = 0; q < 6; ++q) {
            const int m = 1 << q;
            e6 += __shfl_xor(e6, m, 64);
            e7 += __shfl_xor(e7, m, 64);
#pragma unroll
            for (int j = 0; j < q; ++j) {
                E[5 - j] += __shfl_xor(E[5 - j], m, 64);
            }
            const float tpart = __shfl_xor(sum, m, 64);
            const float dd = sum - tpart;
            E[5 - q] = ((lane >> q) & 1) ? -dd : dd;   // wire 5-q
            sum += tpart;
        }
        if (lane == 0) {
            const int b = b0 + s;
            float* ob = (LAYER == 0) ? out + (t * kB + b) * kD + u * kNQ
                                     : out + (b * kT + t) * kD + u * kNQ;
            float4 v0 = make_float4(E[0], E[1], E[2], E[3]);
            float4 v1 = make_float4(E[4], E[5], e6, e7);
            *reinterpret_cast<float4*>(ob)     = v0;
            *reinterpret_cast<float4*>(ob + 4) = v1;
        }
    }
}

}  // namespace

extern "C" void kernel_launch(void* const* d_in, const int* in_sizes, int n_in,
                              void* d_out, int out_size, void* d_ws, size_t ws_size,
                              hipStream_t stream) {
    const float* x     = (const float*)d_in[0];   // (B, T, D) fp32
    const float* theta = (const float*)d_in[1];   // (T, NL, NB, DEPTH, NQ, 3) fp32
    float* out = (float*)d_out;                   // (B, T, D) fp32

    float* gt = (float*)d_ws;                              // 2*64*16*8 floats (64 KB)
    float* h0 = gt + kNL * kCirc * kGates * kGateF;        // (T,B,D) = 131072 floats

    precompute_gates<<<(kNL * kCirc * kGates + 255) / 256, 256, 0, stream>>>(theta, gt);
    // 64 circuits x 256 samples / 2 samples-per-wave = 8192 waves = 2048 blocks
    sim_kernel<0><<<2048, 256, 0, stream>>>(x, gt, h0);
    sim_kernel<1><<<2048, 256, 0, stream>>>(h0, gt, out);
}

// Round 4
// 48.258 us; speedup vs baseline: 1.8695x; 1.5380x over previous
//
#include <hip/hip_runtime.h>

namespace {

constexpr int kT   = 8;    // timesteps
constexpr int kB   = 256;  // batch
constexpr int kNQ  = 8;    // qubits per circuit
constexpr int kNB  = 8;    // blocks
constexpr int kD   = 64;   // features
constexpr int kNL  = 2;    // quantum layers
constexpr int kCirc = kT * kNB;        // 64 circuits per layer
constexpr int kGates = 2 * kNQ;        // 16 Rot gates per circuit
constexpr int kGateF = 8;

// ---------------- Rot-gate precompute ----------------
__global__ void precompute_gates(const float* __restrict__ theta, float* __restrict__ gt) {
    int i = blockIdx.x * blockDim.x + threadIdx.x;
    if (i >= kNL * kCirc * kGates) return;
    int g = i & 15;
    int c = (i >> 4) & 63;
    int l = i >> 10;
    int t = c >> 3, u = c & 7;
    int d = g >> 3, w = g & 7;
    const float* th = theta + ((((t * kNL + l) * kNB + u) * 2 + d) * kNQ + w) * 3;
    float phi = th[0], tht = th[1], omg = th[2];
    float st, ct, sp, cp, sm, cm;
    __sincosf(0.5f * tht, &st, &ct);
    __sincosf(0.5f * (phi + omg), &sp, &cp);
    __sincosf(0.5f * (phi - omg), &sm, &cm);
    float* o = gt + i * kGateF;
    o[0] =  ct * cp;  o[1] = -ct * sp;
    o[2] = -st * cm;  o[3] = -st * sm;
    o[4] =  st * cm;  o[5] = -st * sm;
    o[6] =  ct * cp;  o[7] =  ct * sp;
}

// ---------------- shuffle backends ----------------
template <int CTRL>
__device__ __forceinline__ float f_dpp(float x) {
    return __builtin_bit_cast(float, __builtin_amdgcn_update_dpp(
        0, __builtin_bit_cast(int, x), CTRL, 0xF, 0xF, true));
}
constexpr int kDppXor1 = 0xB1;  // quad_perm [1,0,3,2]
constexpr int kDppXor2 = 0x4E;  // quad_perm [2,3,0,1]

// partner fetch for lane-bit distance: 0=xor1(DPP), 1=xor2(DPP), 2..5=xor4/8/16/32(shfl)
template <int MODE>
__device__ __forceinline__ float lane_partner(float x) {
    if constexpr (MODE == 0) return f_dpp<kDppXor1>(x);
    else if constexpr (MODE == 1) return f_dpp<kDppXor2>(x);
    else if constexpr (MODE == 2) return __shfl_xor(x, 4, 64);
    else if constexpr (MODE == 3) return __shfl_xor(x, 8, 64);
    else if constexpr (MODE == 4) return __shfl_xor(x, 16, 64);
    else return __shfl_xor(x, 32, 64);
}

// ---------------- gate helpers (2 samples/wave, 4 amps/lane) ----------------
// amp index k = (lane<<2)|reg; wire w -> index bit 7-w.
// wires 0..5 -> lane bits 5..0; wires 6,7 -> reg bits 1,0.

template <int MODE>
__device__ __forceinline__ void gate_direct(float (&re)[2][4], float (&im)[2][4], int bit,
                                            float u00r, float u00i, float u01r, float u01i,
                                            float u10r, float u10i, float u11r, float u11i) {
    const float aR = bit ? u11r : u00r;
    const float aI = bit ? u11i : u00i;
    const float bR = bit ? u10r : u01r;
    const float bI = bit ? u10i : u01i;
#pragma unroll
    for (int s = 0; s < 2; ++s)
#pragma unroll
        for (int r = 0; r < 4; ++r) {
            const float pre = lane_partner<MODE>(re[s][r]);
            const float pim = lane_partner<MODE>(im[s][r]);
            const float mre = re[s][r], mim = im[s][r];
            re[s][r] = aR * mre - aI * mim + bR * pre - bI * pim;
            im[s][r] = aR * mim + aI * mre + bR * pim + bI * pre;
        }
}

// register-bit gate (wires 6,7)
template <int PB>
__device__ __forceinline__ void cgate_reg2(float (&re)[2][4], float (&im)[2][4],
                                           float u00r, float u00i, float u01r, float u01i,
                                           float u10r, float u10i, float u11r, float u11i) {
#pragma unroll
    for (int s = 0; s < 2; ++s)
#pragma unroll
        for (int lo = 0; lo < 4; ++lo) {
            if (lo & (1 << PB)) continue;
            const int hi = lo | (1 << PB);
            const float lre = re[s][lo], lim = im[s][lo];
            const float hre = re[s][hi], him = im[s][hi];
            re[s][lo] = u00r * lre - u00i * lim + u01r * hre - u01i * him;
            im[s][lo] = u00r * lim + u00i * lre + u01r * him + u01i * hre;
            re[s][hi] = u10r * lre - u10i * lim + u11r * hre - u11i * him;
            im[s][hi] = u10r * lim + u10i * lre + u11r * him + u11i * hre;
        }
}

// ---------------- main simulation kernel ----------------
// State after AngleEmbedding + depth-0 Rot + CNOT-ring1 is built directly as a
// permuted spinor product (ring1 is a linear basis-index permutation). Then the
// depth-1 Rot gates; CNOT-ring2 is folded into the parity-signed expval reduction.
template <int LAYER>
__global__ __launch_bounds__(256) void sim_kernel(const float* __restrict__ act,
                                                  const float* __restrict__ gt,
                                                  float* __restrict__ out) {
    const int widx = __builtin_amdgcn_readfirstlane(threadIdx.x >> 6);
    const int lane = threadIdx.x & 63;
    const int c  = blockIdx.x >> 5;                        // circuit (block-uniform)
    const int b0 = ((blockIdx.x & 31) << 3) | (widx << 1); // first sample of wave
    const int tt = c >> 3;
    const int u  = c & 7;

    const int l0 = lane & 1,        l1 = (lane >> 1) & 1, l2 = (lane >> 2) & 1;
    const int l3 = (lane >> 3) & 1, l4 = (lane >> 4) & 1, l5 = (lane >> 5) & 1;

    const float* g0 = gt + (size_t)(LAYER * kCirc + c) * kGates * kGateF;  // d=0 gates
    const float* g1 = g0 + 8 * kGateF;                                     // d=1 gates

    float re[2][4], im[2][4];
#pragma unroll
    for (int s = 0; s < 2; ++s) {
        const int b = b0 + s;
        float ang[8];
        if (LAYER == 0) {
            const float* ab = act + (b * kT + tt) * kD + u * kNQ;
#pragma unroll
            for (int w = 0; w < 8; ++w) ang[w] = ab[w];
        } else {
            const float* ab = act + (tt * kB + b) * kD + u;
#pragma unroll
            for (int w = 0; w < 8; ++w) ang[w] = ab[w * kNQ];
        }
        // per-wire spinor after RY(ang) then d0 Rot
        float spr[8][2], spi[8][2];
#pragma unroll
        for (int w = 0; w < 8; ++w) {
            float sn, cs;
            __sincosf(0.5f * ang[w], &sn, &cs);
            const float* gp = g0 + w * kGateF;
            spr[w][0] = gp[0] * cs + gp[2] * sn;
            spi[w][0] = gp[1] * cs + gp[3] * sn;
            spr[w][1] = gp[4] * cs + gp[6] * sn;
            spi[w][1] = gp[5] * cs + gp[7] * sn;
        }
        // ring1 inverse bit map (x = pre-ring1 wire bits; (lane,reg) = post-ring1):
        //  x0=l5^r0  x1=l5^l4^r0  x2=l4^l3  x3=l3^l2  x4=l2^l1  x5=l1^l0
        //  x6=l0^r1  x7=r1^r0
        const int x2 = l4 ^ l3, x3 = l3 ^ l2, x4 = l2 ^ l1, x5 = l1 ^ l0;
        float t1r, t1i, t2r, t2i;
        {
            const float ar = x2 ? spr[2][1] : spr[2][0], ai = x2 ? spi[2][1] : spi[2][0];
            const float br = x3 ? spr[3][1] : spr[3][0], bi = x3 ? spi[3][1] : spi[3][0];
            t1r = ar * br - ai * bi; t1i = ar * bi + ai * br;
        }
        {
            const float ar = x4 ? spr[4][1] : spr[4][0], ai = x4 ? spi[4][1] : spi[4][0];
            const float br = x5 ? spr[5][1] : spr[5][0], bi = x5 ? spi[5][1] : spi[5][0];
            t2r = ar * br - ai * bi; t2i = ar * bi + ai * br;
        }
        const float Lr = t1r * t2r - t1i * t2i, Li = t1r * t2i + t1i * t2r;
        // Q(r0) = s0[l5^r0] * s1[l5^l4^r0]
        const int xa = l5, xb = l5 ^ l4;
        const float a0r = xa ? spr[0][1] : spr[0][0], a0i = xa ? spi[0][1] : spi[0][0];
        const float a1r = xa ? spr[0][0] : spr[0][1], a1i = xa ? spi[0][0] : spi[0][1];
        const float b0r = xb ? spr[1][1] : spr[1][0], b0i = xb ? spi[1][1] : spi[1][0];
        const float b1r = xb ? spr[1][0] : spr[1][1], b1i = xb ? spi[1][0] : spi[1][1];
        const float Q0r = a0r * b0r - a0i * b0i, Q0i = a0r * b0i + a0i * b0r;
        const float Q1r = a1r * b1r - a1i * b1i, Q1i = a1r * b1i + a1i * b1r;
        // R(r1) = s6[l0^r1]; S(r0,r1) = s7[r1^r0]
        const float R0r = l0 ? spr[6][1] : spr[6][0], R0i = l0 ? spi[6][1] : spi[6][0];
        const float R1r = l0 ? spr[6][0] : spr[6][1], R1i = l0 ? spi[6][0] : spi[6][1];
        const float S0r = spr[7][0], S0i = spi[7][0];
        const float S1r = spr[7][1], S1i = spi[7][1];
        float RSr[4], RSi[4];
        RSr[0] = R0r * S0r - R0i * S0i; RSi[0] = R0r * S0i + R0i * S0r;  // r=0
        RSr[1] = R0r * S1r - R0i * S1i; RSi[1] = R0r * S1i + R0i * S1r;  // r=1
        RSr[2] = R1r * S1r - R1i * S1i; RSi[2] = R1r * S1i + R1i * S1r;  // r=2
        RSr[3] = R1r * S0r - R1i * S0i; RSi[3] = R1r * S0i + R1i * S0r;  // r=3
        const float LQ0r = Lr * Q0r - Li * Q0i, LQ0i = Lr * Q0i + Li * Q0r;
        const float LQ1r = Lr * Q1r - Li * Q1i, LQ1i = Lr * Q1i + Li * Q1r;
        re[s][0] = LQ0r * RSr[0] - LQ0i * RSi[0]; im[s][0] = LQ0r * RSi[0] + LQ0i * RSr[0];
        re[s][1] = LQ1r * RSr[1] - LQ1i * RSi[1]; im[s][1] = LQ1r * RSi[1] + LQ1i * RSr[1];
        re[s][2] = LQ0r * RSr[2] - LQ0i * RSi[2]; im[s][2] = LQ0r * RSi[2] + LQ0i * RSr[2];
        re[s][3] = LQ1r * RSr[3] - LQ1i * RSi[3]; im[s][3] = LQ1r * RSi[3] + LQ1i * RSr[3];
    }

    // --- depth-1 Rot gates (wire w on lane bit 5-w) ---
    {
        const float* gp;
        gp = g1 + 0 * kGateF;  // wire0: xor32
        gate_direct<5>(re, im, l5, gp[0], gp[1], gp[2], gp[3], gp[4], gp[5], gp[6], gp[7]);
        gp = g1 + 1 * kGateF;  // wire1: xor16
        gate_direct<4>(re, im, l4, gp[0], gp[1], gp[2], gp[3], gp[4], gp[5], gp[6], gp[7]);
        gp = g1 + 2 * kGateF;  // wire2: xor8
        gate_direct<3>(re, im, l3, gp[0], gp[1], gp[2], gp[3], gp[4], gp[5], gp[6], gp[7]);
        gp = g1 + 3 * kGateF;  // wire3: xor4
        gate_direct<2>(re, im, l2, gp[0], gp[1], gp[2], gp[3], gp[4], gp[5], gp[6], gp[7]);
        gp = g1 + 4 * kGateF;  // wire4: xor2 (DPP)
        gate_direct<1>(re, im, l1, gp[0], gp[1], gp[2], gp[3], gp[4], gp[5], gp[6], gp[7]);
        gp = g1 + 5 * kGateF;  // wire5: xor1 (DPP)
        gate_direct<0>(re, im, l0, gp[0], gp[1], gp[2], gp[3], gp[4], gp[5], gp[6], gp[7]);
        gp = g1 + 6 * kGateF;  // wire6: reg bit 1
        cgate_reg2<1>(re, im, gp[0], gp[1], gp[2], gp[3], gp[4], gp[5], gp[6], gp[7]);
        gp = g1 + 7 * kGateF;  // wire7: reg bit 0
        cgate_reg2<0>(re, im, gp[0], gp[1], gp[2], gp[3], gp[4], gp[5], gp[6], gp[7]);
    }

    // --- ring2 folded into expvals: E_w = sum_x p[x] * (-1)^{g_w(x)} ---
    // g0=l3^l1^r1  g1=l2^l0^r0  g2=l5^l3  g3=l4^l2  g4=l5^l3^l1  g5=l4^l2^l0
    // g6=l5^l3^l1^r1  g7=l4^l2^l0^r0
#pragma unroll
    for (int s = 0; s < 2; ++s) {
        const float p0 = re[s][0] * re[s][0] + im[s][0] * im[s][0];
        const float p1 = re[s][1] * re[s][1] + im[s][1] * im[s][1];
        const float p2 = re[s][2] * re[s][2] + im[s][2] * im[s][2];
        const float p3 = re[s][3] * re[s][3] + im[s][3] * im[s][3];
        float P   = (p0 + p1) + (p2 + p3);   // no reg sign   (E2..E5)
        float R1v = (p0 + p1) - (p2 + p3);   // sign r1       (E0, E6)
        float R0v = (p0 - p1) + (p2 - p3);   // sign r0       (E1, E7)
        float d, Pp;
        // level l0 (xor1, DPP)
        d = f_dpp<kDppXor1>(P);   Pp = P + d; float P0 = P - d; P = Pp;  // spawn E5 (signed l0)
        d = f_dpp<kDppXor1>(R1v); R1v += d;
        d = f_dpp<kDppXor1>(R0v); R0v -= d;
        // level l1 (xor2, DPP)
        d = f_dpp<kDppXor2>(P);   Pp = P + d; float P1 = P - d; P = Pp;  // spawn E4 (signed l1)
        d = f_dpp<kDppXor2>(P0);  P0 += d;
        d = f_dpp<kDppXor2>(R1v); R1v -= d;
        d = f_dpp<kDppXor2>(R0v); R0v += d;
        // level l2 (xor4)
        d = __shfl_xor(P, 4, 64);   Pp = P + d; float P2 = P - d; P = Pp;  // spawn E3 (signed l2)
        d = __shfl_xor(P1, 4, 64);  P1 += d;
        d = __shfl_xor(P0, 4, 64);  P0 -= d;
        d = __shfl_xor(R1v, 4, 64); R1v += d;
        d = __shfl_xor(R0v, 4, 64); R0v -= d;
        // level l3 (xor8)
        d = __shfl_xor(P, 8, 64);   float P3 = P - d;      // spawn E2 (signed l3); P dead
        d = __shfl_xor(P2, 8, 64);  P2 += d;
        d = __shfl_xor(P1, 8, 64);  float P13 = P1 - d;    // E4 signed l3
        d = __shfl_xor(P0, 8, 64);  P0 += d;
        d = __shfl_xor(R1v, 8, 64); R1v -= d;
        d = __shfl_xor(R0v, 8, 64); R0v += d;
        // level l4 (xor16)
        d = __shfl_xor(P3, 16, 64);  P3 += d;
        d = __shfl_xor(P2, 16, 64);  P2 -= d;
        d = __shfl_xor(P13, 16, 64); P13 += d;
        d = __shfl_xor(P0, 16, 64);  P0 -= d;
        d = __shfl_xor(R1v, 16, 64); R1v += d;
        d = __shfl_xor(R0v, 16, 64); const float R0p = R0v + d, R0s = R0v - d;
        // level l5 (xor32)
        d = __shfl_xor(P3, 32, 64);  const float E2 = P3 - d;
        d = __shfl_xor(P2, 32, 64);  const float E3 = P2 + d;
        d = __shfl_xor(P13, 32, 64); const float E4 = P13 - d;
        d = __shfl_xor(P0, 32, 64);  const float E5 = P0 + d;
        d = __shfl_xor(R1v, 32, 64); const float E0 = R1v + d, E6 = R1v - d;
        d = __shfl_xor(R0p, 32, 64); const float E1 = R0p + d;
        d = __shfl_xor(R0s, 32, 64); const float E7 = R0s + d;
        if (lane == 0) {
            const int b = b0 + s;
            float* ob = (LAYER == 0) ? out + (tt * kB + b) * kD + u * kNQ   // H0 (T,B,D)
                                     : out + (b * kT + tt) * kD + u * kNQ;  // final (B,T,D)
            *reinterpret_cast<float4*>(ob)     = make_float4(E0, E1, E2, E3);
            *reinterpret_cast<float4*>(ob + 4) = make_float4(E4, E5, E6, E7);
        }
    }
}

}  // namespace

extern "C" void kernel_launch(void* const* d_in, const int* in_sizes, int n_in,
                              void* d_out, int out_size, void* d_ws, size_t ws_size,
                              hipStream_t stream) {
    const float* x     = (const float*)d_in[0];   // (B, T, D) fp32
    const float* theta = (const float*)d_in[1];   // (T, NL, NB, DEPTH, NQ, 3) fp32
    float* out = (float*)d_out;                   // (B, T, D) fp32

    float* gt = (float*)d_ws;                              // 2*64*16*8 floats (64 KB)
    float* h0 = gt + kNL * kCirc * kGates * kGateF;        // (T,B,D) = 131072 floats

    precompute_gates<<<(kNL * kCirc * kGates + 255) / 256, 256, 0, stream>>>(theta, gt);
    // 64 circuits x 256 samples / 2 samples-per-wave = 8192 waves = 2048 blocks
    sim_kernel<0><<<2048, 256, 0, stream>>>(x, gt, h0);
    sim_kernel<1><<<2048, 256, 0, stream>>>(h0, gt, out);
}

// Round 5
// 37.767 us; speedup vs baseline: 2.3887x; 1.2778x over previous
//
#include <hip/hip_runtime.h>

namespace {

constexpr int kT   = 8;    // timesteps
constexpr int kB   = 256;  // batch
constexpr int kNQ  = 8;    // qubits per circuit
constexpr int kNB  = 8;    // blocks
constexpr int kD   = 64;   // features
constexpr int kNL  = 2;    // quantum layers
constexpr int kCirc = kT * kNB;        // 64 circuits per layer
constexpr int kGates = 2 * kNQ;        // 16 Rot gates per circuit
constexpr int kGateF = 8;

// ---------------- Rot-gate precompute ----------------
__global__ void precompute_gates(const float* __restrict__ theta, float* __restrict__ gt) {
    int i = blockIdx.x * blockDim.x + threadIdx.x;
    if (i >= kNL * kCirc * kGates) return;
    int g = i & 15;
    int c = (i >> 4) & 63;
    int l = i >> 10;
    int t = c >> 3, u = c & 7;
    int d = g >> 3, w = g & 7;
    const float* th = theta + ((((t * kNL + l) * kNB + u) * 2 + d) * kNQ + w) * 3;
    float phi = th[0], tht = th[1], omg = th[2];
    float st, ct, sp, cp, sm, cm;
    __sincosf(0.5f * tht, &st, &ct);
    __sincosf(0.5f * (phi + omg), &sp, &cp);
    __sincosf(0.5f * (phi - omg), &sm, &cm);
    float* o = gt + i * kGateF;
    o[0] =  ct * cp;  o[1] = -ct * sp;
    o[2] = -st * cm;  o[3] = -st * sm;
    o[4] =  st * cm;  o[5] = -st * sm;
    o[6] =  ct * cp;  o[7] =  ct * sp;
}

// ---------------- shuffle backends ----------------
template <int CTRL>
__device__ __forceinline__ float f_dpp(float x) {
    return __builtin_bit_cast(float, __builtin_amdgcn_update_dpp(
        0, __builtin_bit_cast(int, x), CTRL, 0xF, 0xF, true));
}
constexpr int kDppXor1 = 0xB1;  // quad_perm [1,0,3,2]
constexpr int kDppXor2 = 0x4E;  // quad_perm [2,3,0,1]

// partner fetch at lane distance 1<<MODE: 0,1 via DPP (VALU); 2..5 via shfl (DS)
template <int MODE>
__device__ __forceinline__ float lane_partner(float x) {
    if constexpr (MODE == 0) return f_dpp<kDppXor1>(x);
    else if constexpr (MODE == 1) return f_dpp<kDppXor2>(x);
    else if constexpr (MODE == 2) return __shfl_xor(x, 4, 64);
    else if constexpr (MODE == 3) return __shfl_xor(x, 8, 64);
    else if constexpr (MODE == 4) return __shfl_xor(x, 16, 64);
    else return __shfl_xor(x, 32, 64);
}

// one Walsh-Hadamard butterfly level: v' = partner + (-1)^{lane bit Q} * v
template <int Q>
__device__ __forceinline__ float wht_level(float v, unsigned sgn) {
    const float d = lane_partner<Q>(v);
    return d + __builtin_bit_cast(float, __builtin_bit_cast(unsigned, v) ^ sgn);
}

// ---------------- gate helpers (2 samples/wave, 4 amps/lane) ----------------
// amp index k = (lane<<2)|reg; wire w -> index bit 7-w.
// wires 0..5 -> lane bits 5..0; wires 6,7 -> reg bits 1,0.

template <int MODE>
__device__ __forceinline__ void gate_direct(float (&re)[2][4], float (&im)[2][4], int bit,
                                            float u00r, float u00i, float u01r, float u01i,
                                            float u10r, float u10i, float u11r, float u11i) {
    const float aR = bit ? u11r : u00r;
    const float aI = bit ? u11i : u00i;
    const float bR = bit ? u10r : u01r;
    const float bI = bit ? u10i : u01i;
#pragma unroll
    for (int s = 0; s < 2; ++s)
#pragma unroll
        for (int r = 0; r < 4; ++r) {
            const float pre = lane_partner<MODE>(re[s][r]);
            const float pim = lane_partner<MODE>(im[s][r]);
            const float mre = re[s][r], mim = im[s][r];
            re[s][r] = aR * mre - aI * mim + bR * pre - bI * pim;
            im[s][r] = aR * mim + aI * mre + bR * pim + bI * pre;
        }
}

// register-bit gate (wires 6,7)
template <int PB>
__device__ __forceinline__ void cgate_reg2(float (&re)[2][4], float (&im)[2][4],
                                           float u00r, float u00i, float u01r, float u01i,
                                           float u10r, float u10i, float u11r, float u11i) {
#pragma unroll
    for (int s = 0; s < 2; ++s)
#pragma unroll
        for (int lo = 0; lo < 4; ++lo) {
            if (lo & (1 << PB)) continue;
            const int hi = lo | (1 << PB);
            const float lre = re[s][lo], lim = im[s][lo];
            const float hre = re[s][hi], him = im[s][hi];
            re[s][lo] = u00r * lre - u00i * lim + u01r * hre - u01i * him;
            im[s][lo] = u00r * lim + u00i * lre + u01r * him + u01i * hre;
            re[s][hi] = u10r * lre - u10i * lim + u11r * hre - u11i * him;
            im[s][hi] = u10r * lim + u10i * lre + u11r * him + u11i * hre;
        }
}

// ---------------- one circuit sim: 2 samples, output = 3 Walsh streams ----------------
// State after AngleEmbedding + depth-0 Rot + CNOT-ring1 built directly as a permuted
// spinor product; depth-1 Rot gates applied; CNOT-ring2 folded into Walsh parities.
__device__ __forceinline__ void sim2(const float (&ang)[2][8],
                                     const float* __restrict__ g0,
                                     const float* __restrict__ g1,
                                     int lane, const unsigned (&sg)[6],
                                     float (&WP)[2], float (&WR1)[2], float (&WR0)[2]) {
    const int l0 = lane & 1,        l1 = (lane >> 1) & 1, l2 = (lane >> 2) & 1;
    const int l3 = (lane >> 3) & 1, l4 = (lane >> 4) & 1, l5 = (lane >> 5) & 1;

    float re[2][4], im[2][4];
#pragma unroll
    for (int s = 0; s < 2; ++s) {
        // per-wire spinor after RY(ang) then d0 Rot
        float spr[8][2], spi[8][2];
#pragma unroll
        for (int w = 0; w < 8; ++w) {
            float sn, cs;
            __sincosf(0.5f * ang[s][w], &sn, &cs);
            const float* gp = g0 + w * kGateF;
            spr[w][0] = gp[0] * cs + gp[2] * sn;
            spi[w][0] = gp[1] * cs + gp[3] * sn;
            spr[w][1] = gp[4] * cs + gp[6] * sn;
            spi[w][1] = gp[5] * cs + gp[7] * sn;
        }
        // ring1 inverse bit map (x = pre-ring1 wire bits; (lane,reg) = post-ring1):
        //  x0=l5^r0  x1=l5^l4^r0  x2=l4^l3  x3=l3^l2  x4=l2^l1  x5=l1^l0
        //  x6=l0^r1  x7=r1^r0
        const int x2 = l4 ^ l3, x3 = l3 ^ l2, x4 = l2 ^ l1, x5 = l1 ^ l0;
        float t1r, t1i, t2r, t2i;
        {
            const float ar = x2 ? spr[2][1] : spr[2][0], ai = x2 ? spi[2][1] : spi[2][0];
            const float br = x3 ? spr[3][1] : spr[3][0], bi = x3 ? spi[3][1] : spi[3][0];
            t1r = ar * br - ai * bi; t1i = ar * bi + ai * br;
        }
        {
            const float ar = x4 ? spr[4][1] : spr[4][0], ai = x4 ? spi[4][1] : spi[4][0];
            const float br = x5 ? spr[5][1] : spr[5][0], bi = x5 ? spi[5][1] : spi[5][0];
            t2r = ar * br - ai * bi; t2i = ar * bi + ai * br;
        }
        const float Lr = t1r * t2r - t1i * t2i, Li = t1r * t2i + t1i * t2r;
        // Q(r0) = s0[l5^r0] * s1[l5^l4^r0]
        const int xa = l5, xb = l5 ^ l4;
        const float a0r = xa ? spr[0][1] : spr[0][0], a0i = xa ? spi[0][1] : spi[0][0];
        const float a1r = xa ? spr[0][0] : spr[0][1], a1i = xa ? spi[0][0] : spi[0][1];
        const float b0r = xb ? spr[1][1] : spr[1][0], b0i = xb ? spi[1][1] : spi[1][0];
        const float b1r = xb ? spr[1][0] : spr[1][1], b1i = xb ? spi[1][0] : spi[1][1];
        const float Q0r = a0r * b0r - a0i * b0i, Q0i = a0r * b0i + a0i * b0r;
        const float Q1r = a1r * b1r - a1i * b1i, Q1i = a1r * b1i + a1i * b1r;
        // R(r1) = s6[l0^r1]; S(r0,r1) = s7[r1^r0]
        const float R0r = l0 ? spr[6][1] : spr[6][0], R0i = l0 ? spi[6][1] : spi[6][0];
        const float R1r = l0 ? spr[6][0] : spr[6][1], R1i = l0 ? spi[6][0] : spi[6][1];
        const float S0r = spr[7][0], S0i = spi[7][0];
        const float S1r = spr[7][1], S1i = spi[7][1];
        float RSr[4], RSi[4];
        RSr[0] = R0r * S0r - R0i * S0i; RSi[0] = R0r * S0i + R0i * S0r;  // r=0
        RSr[1] = R0r * S1r - R0i * S1i; RSi[1] = R0r * S1i + R0i * S1r;  // r=1
        RSr[2] = R1r * S1r - R1i * S1i; RSi[2] = R1r * S1i + R1i * S1r;  // r=2
        RSr[3] = R1r * S0r - R1i * S0i; RSi[3] = R1r * S0i + R1i * S0r;  // r=3
        const float LQ0r = Lr * Q0r - Li * Q0i, LQ0i = Lr * Q0i + Li * Q0r;
        const float LQ1r = Lr * Q1r - Li * Q1i, LQ1i = Lr * Q1i + Li * Q1r;
        re[s][0] = LQ0r * RSr[0] - LQ0i * RSi[0]; im[s][0] = LQ0r * RSi[0] + LQ0i * RSr[0];
        re[s][1] = LQ1r * RSr[1] - LQ1i * RSi[1]; im[s][1] = LQ1r * RSi[1] + LQ1i * RSr[1];
        re[s][2] = LQ0r * RSr[2] - LQ0i * RSi[2]; im[s][2] = LQ0r * RSi[2] + LQ0i * RSr[2];
        re[s][3] = LQ1r * RSr[3] - LQ1i * RSi[3]; im[s][3] = LQ1r * RSi[3] + LQ1i * RSr[3];
    }

    // --- depth-1 Rot gates (wire w on lane bit 5-w) ---
    {
        const float* gp;
        gp = g1 + 0 * kGateF;  // wire0: xor32
        gate_direct<5>(re, im, l5, gp[0], gp[1], gp[2], gp[3], gp[4], gp[5], gp[6], gp[7]);
        gp = g1 + 1 * kGateF;  // wire1: xor16
        gate_direct<4>(re, im, l4, gp[0], gp[1], gp[2], gp[3], gp[4], gp[5], gp[6], gp[7]);
        gp = g1 + 2 * kGateF;  // wire2: xor8
        gate_direct<3>(re, im, l3, gp[0], gp[1], gp[2], gp[3], gp[4], gp[5], gp[6], gp[7]);
        gp = g1 + 3 * kGateF;  // wire3: xor4
        gate_direct<2>(re, im, l2, gp[0], gp[1], gp[2], gp[3], gp[4], gp[5], gp[6], gp[7]);
        gp = g1 + 4 * kGateF;  // wire4: xor2 (DPP)
        gate_direct<1>(re, im, l1, gp[0], gp[1], gp[2], gp[3], gp[4], gp[5], gp[6], gp[7]);
        gp = g1 + 5 * kGateF;  // wire5: xor1 (DPP)
        gate_direct<0>(re, im, l0, gp[0], gp[1], gp[2], gp[3], gp[4], gp[5], gp[6], gp[7]);
        gp = g1 + 6 * kGateF;  // wire6: reg bit 1
        cgate_reg2<1>(re, im, gp[0], gp[1], gp[2], gp[3], gp[4], gp[5], gp[6], gp[7]);
        gp = g1 + 7 * kGateF;  // wire7: reg bit 0
        cgate_reg2<0>(re, im, gp[0], gp[1], gp[2], gp[3], gp[4], gp[5], gp[6], gp[7]);
    }

    // --- ring2 folded into Walsh parities: E_w = W_stream[mask_w] ---
    // g0=l3^l1^r1  g1=l2^l0^r0  g2=l5^l3  g3=l4^l2  g4=l5^l3^l1  g5=l4^l2^l0
    // g6=l5^l3^l1^r1  g7=l4^l2^l0^r0
    // Full WHT butterfly leaves W[m] at lane m for each stream.
#pragma unroll
    for (int s = 0; s < 2; ++s) {
        const float p0 = re[s][0] * re[s][0] + im[s][0] * im[s][0];
        const float p1 = re[s][1] * re[s][1] + im[s][1] * im[s][1];
        const float p2 = re[s][2] * re[s][2] + im[s][2] * im[s][2];
        const float p3 = re[s][3] * re[s][3] + im[s][3] * im[s][3];
        float P  = (p0 + p1) + (p2 + p3);   // no reg sign
        float R1 = (p0 + p1) - (p2 + p3);   // reg-bit-1 sign
        float R0 = (p0 - p1) + (p2 - p3);   // reg-bit-0 sign
        P  = wht_level<0>(P,  sg[0]); P  = wht_level<1>(P,  sg[1]);
        P  = wht_level<2>(P,  sg[2]); P  = wht_level<3>(P,  sg[3]);
        P  = wht_level<4>(P,  sg[4]); P  = wht_level<5>(P,  sg[5]);
        R1 = wht_level<0>(R1, sg[0]); R1 = wht_level<1>(R1, sg[1]);
        R1 = wht_level<2>(R1, sg[2]); R1 = wht_level<3>(R1, sg[3]);
        R1 = wht_level<4>(R1, sg[4]); R1 = wht_level<5>(R1, sg[5]);
        R0 = wht_level<0>(R0, sg[0]); R0 = wht_level<1>(R0, sg[1]);
        R0 = wht_level<2>(R0, sg[2]); R0 = wht_level<3>(R0, sg[3]);
        R0 = wht_level<4>(R0, sg[4]); R0 = wht_level<5>(R0, sg[5]);
        WP[s] = P; WR1[s] = R1; WR0[s] = R0;
    }
}

// scatter the 8 expvals (E_w = Walsh coeffs at fixed lanes) to e[0..7]
template <typename PT>
__device__ __forceinline__ void scatter_ev(PT e, int lane, float P, float R1, float R0) {
    if (lane == 10) e[0] = R1;                  // E0: R1 @ mask l3^l1 = 10
    if (lane ==  5) e[1] = R0;                  // E1: R0 @ l2^l0 = 5
    if (lane == 40) e[2] = P;                   // E2: P  @ l5^l3 = 40
    if (lane == 20) e[3] = P;                   // E3: P  @ l4^l2 = 20
    if (lane == 42) { e[4] = P; e[6] = R1; }    // E4: P @ 42; E6: R1 @ 42
    if (lane == 21) { e[5] = P; e[7] = R0; }    // E5: P @ 21; E7: R0 @ 21
}

// ---------------- fused both-layer kernel ----------------
// block = 512 threads = 8 waves = the 8 circuits of one (t, sample-pair);
// layer-0 results exchanged through 512 B of LDS.
__global__ __launch_bounds__(512) void fused_kernel(const float* __restrict__ x,
                                                    const float* __restrict__ gt,
                                                    float* __restrict__ out) {
    const int widx = __builtin_amdgcn_readfirstlane(threadIdx.x >> 6);  // circuit u
    const int lane = threadIdx.x & 63;
    const int tt = blockIdx.x >> 7;          // timestep
    const int b0 = (blockIdx.x & 127) << 1;  // first sample of pair

    __shared__ float exch[2][8][8];          // [sample][block i][wire w]

    unsigned sg[6];
#pragma unroll
    for (int q = 0; q < 6; ++q) sg[q] = ((lane >> q) & 1u) << 31;

    const int c = tt * kNB + widx;
    float WP[2], WR1[2], WR0[2];
    float ang[2][8];

    // ---- phase 0: layer-0 circuit (t, widx), samples b0, b0+1 ----
    {
        const float* g0 = gt + (size_t)c * kGates * kGateF;
        const float* g1 = g0 + 8 * kGateF;
#pragma unroll
        for (int s = 0; s < 2; ++s) {
            const float* ab = x + ((b0 + s) * kT + tt) * kD + widx * kNQ;
#pragma unroll
            for (int w = 0; w < 8; ++w) ang[s][w] = ab[w];
        }
        sim2(ang, g0, g1, lane, sg, WP, WR1, WR0);
#pragma unroll
        for (int s = 0; s < 2; ++s)
            scatter_ev(&exch[s][widx][0], lane, WP[s], WR1[s], WR0[s]);
    }
    __syncthreads();
    // ---- phase 1: layer-1 circuit (t, widx) gathers feature widx of every block ----
    {
        const float* g0 = gt + (size_t)(kCirc + c) * kGates * kGateF;
        const float* g1 = g0 + 8 * kGateF;
#pragma unroll
        for (int s = 0; s < 2; ++s)
#pragma unroll
            for (int i = 0; i < 8; ++i) ang[s][i] = exch[s][i][widx];
        sim2(ang, g0, g1, lane, sg, WP, WR1, WR0);
#pragma unroll
        for (int s = 0; s < 2; ++s)
            scatter_ev(out + ((b0 + s) * kT + tt) * kD + widx * kNQ, lane,
                       WP[s], WR1[s], WR0[s]);
    }
}

}  // namespace

extern "C" void kernel_launch(void* const* d_in, const int* in_sizes, int n_in,
                              void* d_out, int out_size, void* d_ws, size_t ws_size,
                              hipStream_t stream) {
    const float* x     = (const float*)d_in[0];   // (B, T, D) fp32
    const float* theta = (const float*)d_in[1];   // (T, NL, NB, DEPTH, NQ, 3) fp32
    float* out = (float*)d_out;                   // (B, T, D) fp32

    float* gt = (float*)d_ws;                     // gate table: 2*64*16*8 floats (64 KB)

    precompute_gates<<<(kNL * kCirc * kGates + 255) / 256, 256, 0, stream>>>(theta, gt);
    // 8 timesteps x 128 sample-pairs; 512 threads = 8 circuits x (2 samples/wave)
    fused_kernel<<<kT * (kB / 2), 512, 0, stream>>>(x, gt, out);
}